// Round 1
// baseline (108.302 us; speedup 1.0000x reference)
//
#include <hip/hip_runtime.h>
#include <math.h>

// One wave64 per batch element. State psi (4096 fp32) lives entirely in VGPRs:
// flat index bits [11:6] = lane id (qubits 0..5), bits [5:0] = register id
// (qubits 6..11).  Qubit l <-> flat bit (11-l).
//
// rot_block fusion: all 10 crY(theta_i, i -> 10) + rY(theta_10) are rotations
// about Y on qubit 10 controlled in the computational basis -> they commute and
// fuse to a single rY(theta_10 + sum x_i theta_i).  Per neuron we precompute the
// 16 (cos,sin) pairs over qubits 6..9 combos (lane part added into the base
// angle), reused by all 4 rot_blocks (sign flip only).
// BitFlip layer folds into the initial load address (XOR of lane bits) for free.

__device__ __forceinline__ void reg_ry_m(float (&v)[64], int MT, float c, float s);

template <int MT>
__device__ __forceinline__ void reg_ry(float (&v)[64], float c, float s) {
    // uncontrolled rY on register-bit qubit with mask MT
#pragma unroll
    for (int r = 0; r < 64; ++r) {
        if (!(r & MT)) {
            float a0 = v[r], a1 = v[r | MT];
            v[r]      = c * a0 - s * a1;
            v[r | MT] = s * a0 + c * a1;
        }
    }
}

__device__ __forceinline__ void lane_ry(float (&v)[64], int lm, float c, float s, int ln) {
    // uncontrolled rY on lane-bit qubit (cross-lane via shfl_xor)
    float ss = (ln & lm) ? s : -s;
#pragma unroll
    for (int r = 0; r < 64; ++r) {
        float p = __shfl_xor(v[r], lm, 64);
        v[r] = c * v[r] + ss * p;
    }
}

__device__ __forceinline__ void rot_block_apply(float (&v)[64], const float (&c16)[16],
                                                const float (&s16)[16], float sg) {
    // fused rY(phi) on qubit 10 (reg bit 1); pairs (4h,4h+2) and (4h+1,4h+3)
#pragma unroll
    for (int h = 0; h < 16; ++h) {
        float c = c16[h];
        float s = sg * s16[h];
        int r0 = 4 * h;
        float a0 = v[r0], a1 = v[r0 + 2];
        v[r0]     = c * a0 - s * a1;
        v[r0 + 2] = s * a0 + c * a1;
        float b0 = v[r0 + 1], b1 = v[r0 + 3];
        v[r0 + 1] = c * b0 - s * b1;
        v[r0 + 3] = s * b0 + c * b1;
    }
}

__device__ __forceinline__ void cry_pi_10_11(float (&v)[64], float sg) {
    // crY(sg*pi), control qubit 10 (bit1==1), target qubit 11 (bit0); c=0,s=sg
#pragma unroll
    for (int r = 2; r < 64; r += 4) {
        float a0 = v[r], a1 = v[r + 1];
        v[r]     = -sg * a1;
        v[r + 1] =  sg * a0;
    }
}

template <int MT>
__device__ __forceinline__ void cry_pi_11_reg(float (&v)[64], float sg) {
    // crY(sg*pi), control qubit 11 (bit0==1), target = register-bit qubit mask MT
#pragma unroll
    for (int r = 1; r < 64; r += 2) {
        if (!(r & MT)) {
            float a0 = v[r], a1 = v[r | MT];
            v[r]      = -sg * a1;
            v[r | MT] =  sg * a0;
        }
    }
}

__device__ __forceinline__ void cry_pi_11_lane(float (&v)[64], int lm, float sg, int ln) {
    // crY(sg*pi), control qubit 11 (bit0==1), target = lane-bit qubit mask lm
    float ss = (ln & lm) ? sg : -sg;
#pragma unroll
    for (int r = 1; r < 64; r += 2) {
        float p = __shfl_xor(v[r], lm, 64);
        v[r] = ss * p;
    }
}

__global__ __launch_bounds__(64) void rvqe_kernel(
    const float* __restrict__ psi_in,   // (B, 4096)
    const int*   __restrict__ inp,      // (6,)
    const float* __restrict__ ut,       // (2, 10)
    const float* __restrict__ nt,       // (2, 10, 11)
    float* __restrict__ out_probs,      // (B, 64)
    float* __restrict__ out_psi)        // (B, 4096)
{
    const int b  = blockIdx.x;
    const int ln = threadIdx.x & 63;

    // BitFlip layer: fold X on input lanes into load address (lane bits 5..0
    // correspond to qubits 0..5).
    int flip = 0;
#pragma unroll
    for (int l = 0; l < 6; ++l)
        if (inp[l] == 1) flip |= 1 << (5 - l);

    float v[64];
    const float* src = psi_in + (size_t)b * 4096 + (((ln ^ flip) & 63) << 6);
#pragma unroll
    for (int q = 0; q < 16; ++q) {
        float4 t = ((const float4*)src)[q];
        v[4 * q + 0] = t.x;
        v[4 * q + 1] = t.y;
        v[4 * q + 2] = t.z;
        v[4 * q + 3] = t.w;
    }

    for (int s = 0; s < 2; ++s) {
        const float* uts = ut + s * 10;
        // ---- UnitaryLayer: rY(uts[i]) on qubit i ----
#pragma unroll
        for (int i = 0; i < 6; ++i) {
            float cc, ss;
            __sincosf(0.5f * uts[i], &ss, &cc);
            lane_ry(v, 1 << (5 - i), cc, ss, ln);
        }
        {
            float cc, ss;
            __sincosf(0.5f * uts[6], &ss, &cc); reg_ry<32>(v, cc, ss);
            __sincosf(0.5f * uts[7], &ss, &cc); reg_ry<16>(v, cc, ss);
            __sincosf(0.5f * uts[8], &ss, &cc); reg_ry<8>(v, cc, ss);
            __sincosf(0.5f * uts[9], &ss, &cc); reg_ry<4>(v, cc, ss);
        }

        // ---- QuantumNeuronLayer per out lane ----
        for (int out = 0; out < 10; ++out) {
            const float* th = nt + (size_t)(s * 10 + out) * 11;

            // base angle from lane-bit qubits 0..5 + bias
            float phib = th[10];
#pragma unroll
            for (int i = 0; i < 6; ++i)
                if ((ln >> (5 - i)) & 1) phib += th[i];

            // 16 combos over qubits 6..9 (h = r>>2; h bit3 -> qubit6, ...)
            float c16[16], s16[16];
#pragma unroll
            for (int h = 0; h < 16; ++h) {
                float ang = phib;
                if (h & 8) ang += th[6];
                if (h & 4) ang += th[7];
                if (h & 2) ang += th[8];
                if (h & 1) ang += th[9];
                __sincosf(0.5f * ang, &s16[h], &c16[h]);
            }

            // RB(+), crY(+pi,10,11), RB(-), crY(+pi,11,out), RB(+),
            // crY(-pi,10,11), RB(-)
            rot_block_apply(v, c16, s16, 1.f);
            cry_pi_10_11(v, 1.f);
            rot_block_apply(v, c16, s16, -1.f);

            if (out < 6) {
                cry_pi_11_lane(v, 1 << (5 - out), 1.f, ln);
            } else {
                switch (out) {
                    case 6: cry_pi_11_reg<32>(v, 1.f); break;
                    case 7: cry_pi_11_reg<16>(v, 1.f); break;
                    case 8: cry_pi_11_reg<8>(v, 1.f); break;
                    default: cry_pi_11_reg<4>(v, 1.f); break;
                }
            }

            rot_block_apply(v, c16, s16, 1.f);
            cry_pi_10_11(v, -1.f);
            rot_block_apply(v, c16, s16, -1.f);
        }
    }

    // ---- probs: marginal |amp|^2 over qubits 6..11 (the registers) ----
    float acc = 0.f;
#pragma unroll
    for (int r = 0; r < 64; ++r) acc += v[r] * v[r];
    out_probs[(size_t)b * 64 + ln] = acc;

    // ---- write final psi ----
    float* dst = out_psi + (size_t)b * 4096 + (ln << 6);
#pragma unroll
    for (int q = 0; q < 16; ++q) {
        ((float4*)dst)[q] =
            make_float4(v[4 * q + 0], v[4 * q + 1], v[4 * q + 2], v[4 * q + 3]);
    }
}

extern "C" void kernel_launch(void* const* d_in, const int* in_sizes, int n_in,
                              void* d_out, int out_size, void* d_ws, size_t ws_size,
                              hipStream_t stream) {
    const float* psi = (const float*)d_in[0];
    const int*   inp = (const int*)d_in[1];
    const float* ut  = (const float*)d_in[2];
    const float* nt  = (const float*)d_in[3];

    const int B = in_sizes[0] >> 12;          // 4096 amplitudes per state
    float* probs   = (float*)d_out;           // (B, 64) first
    float* opsi    = probs + (size_t)B * 64;  // then (B, 4096)

    rvqe_kernel<<<B, 64, 0, stream>>>(psi, inp, ut, nt, probs, opsi);
}

// Round 2
// 94.508 us; speedup vs baseline: 1.1460x; 1.1460x over previous
//
#include <hip/hip_runtime.h>
#include <math.h>

// 4 waves (256 threads) per batch element. State psi (4096 fp32) split:
//   flat bits [11:6] = lane id   (qubits 0..5)
//   flat bits [5:4]  = wave id   (qubits 6..7)   <- cross-wave via LDS (rare)
//   flat bits [3:0]  = reg  id   (qubits 8..11)  <- in-register
// Qubit l <-> flat bit (11-l).
//
// rot_block fusion: all 10 crY(theta_i, i->10) + rY(theta_10) commute (all are
// Y-rotations on qubit 10 controlled in the computational basis) and fuse to a
// single rY(theta_10 + sum x_i theta_i). Lane bits + wave bits fold into the
// base angle; only qubits 8,9 (reg bits 3,2) need the 4-combo sincos table.
// BitFlip layer folds into the initial load address.

#define LN_STRIDE 20  // floats per lane slot in LDS (pad: 20%32 banks spread)

template <int MT>
__device__ __forceinline__ void reg_ry(float (&v)[16], float c, float s) {
#pragma unroll
    for (int r = 0; r < 16; ++r) {
        if (!(r & MT)) {
            float a0 = v[r], a1 = v[r | MT];
            v[r]      = c * a0 - s * a1;
            v[r | MT] = s * a0 + c * a1;
        }
    }
}

__device__ __forceinline__ void lane_ry(float (&v)[16], int lm, float c, float s, int ln) {
    float ss = (ln & lm) ? s : -s;
#pragma unroll
    for (int r = 0; r < 16; ++r) {
        float p = __shfl_xor(v[r], lm, 64);
        v[r] = c * v[r] + ss * p;
    }
}

// cross-wave uncontrolled rY on wave-bit qubit (wbit = 2 -> qubit6, 1 -> qubit7)
__device__ __forceinline__ void wave_ry(float (&v)[16], int wbit, float c, float s,
                                        int wv, int ln, float* xbuf) {
    float* my = xbuf + (wv * 64 + ln) * LN_STRIDE;
    __syncthreads();  // previous buffer consumers done
#pragma unroll
    for (int q = 0; q < 4; ++q)
        ((float4*)my)[q] = make_float4(v[4*q], v[4*q+1], v[4*q+2], v[4*q+3]);
    __syncthreads();
    const float* pr = xbuf + ((wv ^ wbit) * 64 + ln) * LN_STRIDE;
    float ss = (wv & wbit) ? s : -s;
#pragma unroll
    for (int q = 0; q < 4; ++q) {
        float4 p = ((const float4*)pr)[q];
        v[4*q+0] = c * v[4*q+0] + ss * p.x;
        v[4*q+1] = c * v[4*q+1] + ss * p.y;
        v[4*q+2] = c * v[4*q+2] + ss * p.z;
        v[4*q+3] = c * v[4*q+3] + ss * p.w;
    }
}

// cross-wave crY(sg*pi): control qubit 11 (r bit0==1), target wave-bit qubit
__device__ __forceinline__ void wave_cry_pi(float (&v)[16], int wbit, float sg,
                                            int wv, int ln, float* xbuf) {
    float* my = xbuf + (wv * 64 + ln) * LN_STRIDE;
    __syncthreads();
#pragma unroll
    for (int q = 0; q < 4; ++q)
        ((float4*)my)[q] = make_float4(v[4*q], v[4*q+1], v[4*q+2], v[4*q+3]);
    __syncthreads();
    const float* pr = xbuf + ((wv ^ wbit) * 64 + ln) * LN_STRIDE;
    float ss = (wv & wbit) ? sg : -sg;
#pragma unroll
    for (int q = 0; q < 4; ++q) {
        float4 p = ((const float4*)pr)[q];
        v[4*q+1] = ss * p.y;   // odd r only (control bit set)
        v[4*q+3] = ss * p.w;
    }
}

// fused rY(phi) on qubit 10 (r bit1); pairs (4h+j, 4h+2+j), h = qubits 8,9
__device__ __forceinline__ void rot_block_apply(float (&v)[16], const float (&c4)[4],
                                                const float (&s4)[4], float sg) {
#pragma unroll
    for (int h = 0; h < 4; ++h) {
        float c = c4[h];
        float s = sg * s4[h];
        int r0 = 4 * h;
        float a0 = v[r0], a1 = v[r0 + 2];
        v[r0]     = c * a0 - s * a1;
        v[r0 + 2] = s * a0 + c * a1;
        float b0 = v[r0 + 1], b1 = v[r0 + 3];
        v[r0 + 1] = c * b0 - s * b1;
        v[r0 + 3] = s * b0 + c * b1;
    }
}

// crY(sg*pi), control qubit 10 (r bit1==1), target qubit 11 (r bit0)
__device__ __forceinline__ void cry_pi_10_11(float (&v)[16], float sg) {
#pragma unroll
    for (int r = 2; r < 16; r += 4) {
        float a0 = v[r], a1 = v[r + 1];
        v[r]     = -sg * a1;
        v[r + 1] =  sg * a0;
    }
}

// crY(sg*pi), control qubit 11 (r bit0==1), target reg-bit qubit mask MT (8 or 4)
template <int MT>
__device__ __forceinline__ void cry_pi_11_reg(float (&v)[16], float sg) {
#pragma unroll
    for (int r = 1; r < 16; r += 2) {
        if (!(r & MT)) {
            float a0 = v[r], a1 = v[r | MT];
            v[r]      = -sg * a1;
            v[r | MT] =  sg * a0;
        }
    }
}

// crY(sg*pi), control qubit 11, target lane-bit qubit mask lm
__device__ __forceinline__ void cry_pi_11_lane(float (&v)[16], int lm, float sg, int ln) {
    float ss = (ln & lm) ? sg : -sg;
#pragma unroll
    for (int r = 1; r < 16; r += 2) {
        float p = __shfl_xor(v[r], lm, 64);
        v[r] = ss * p;
    }
}

__global__ __launch_bounds__(256) void rvqe_kernel(
    const float* __restrict__ psi_in,   // (B, 4096)
    const int*   __restrict__ inp,      // (6,)
    const float* __restrict__ ut,       // (2, 10)
    const float* __restrict__ nt,       // (2, 10, 11)
    float* __restrict__ out_probs,      // (B, 64)
    float* __restrict__ out_psi)        // (B, 4096)
{
    __shared__ float xbuf[4 * 64 * LN_STRIDE];  // 20 KB

    const int b   = blockIdx.x;
    const int tid = threadIdx.x;
    const int ln  = tid & 63;
    const int wv  = tid >> 6;       // bit1 = qubit6 value, bit0 = qubit7 value

    // BitFlip: fold X on input lanes into load address
    int flip = 0;
#pragma unroll
    for (int l = 0; l < 6; ++l)
        if (inp[l] == 1) flip |= 1 << (5 - l);

    float v[16];
    const float* src = psi_in + (size_t)b * 4096 + (((ln ^ flip) & 63) << 6) + (wv << 4);
#pragma unroll
    for (int q = 0; q < 4; ++q) {
        float4 t = ((const float4*)src)[q];
        v[4*q+0] = t.x; v[4*q+1] = t.y; v[4*q+2] = t.z; v[4*q+3] = t.w;
    }

    for (int s = 0; s < 2; ++s) {
        const float* uts = ut + s * 10;
        // ---- UnitaryLayer ----
#pragma unroll
        for (int i = 0; i < 6; ++i) {
            float cc, ss;
            __sincosf(0.5f * uts[i], &ss, &cc);
            lane_ry(v, 1 << (5 - i), cc, ss, ln);
        }
        {
            float cc, ss;
            __sincosf(0.5f * uts[6], &ss, &cc); wave_ry(v, 2, cc, ss, wv, ln, xbuf);
            __sincosf(0.5f * uts[7], &ss, &cc); wave_ry(v, 1, cc, ss, wv, ln, xbuf);
            __sincosf(0.5f * uts[8], &ss, &cc); reg_ry<8>(v, cc, ss);
            __sincosf(0.5f * uts[9], &ss, &cc); reg_ry<4>(v, cc, ss);
        }

        // ---- QuantumNeuronLayer per out lane ----
        for (int out = 0; out < 10; ++out) {
            const float* th = nt + (size_t)(s * 10 + out) * 11;

            // base angle: bias + lane bits (qubits 0..5) + wave bits (qubits 6,7)
            float phib = th[10];
#pragma unroll
            for (int i = 0; i < 6; ++i)
                if ((ln >> (5 - i)) & 1) phib += th[i];
            if (wv & 2) phib += th[6];
            if (wv & 1) phib += th[7];

            // 4 combos over qubits 8,9 (h = r>>2; h bit1 -> q8, bit0 -> q9)
            float c4[4], s4[4];
#pragma unroll
            for (int h = 0; h < 4; ++h) {
                float ang = phib;
                if (h & 2) ang += th[8];
                if (h & 1) ang += th[9];
                __sincosf(0.5f * ang, &s4[h], &c4[h]);
            }

            rot_block_apply(v, c4, s4, 1.f);
            cry_pi_10_11(v, 1.f);
            rot_block_apply(v, c4, s4, -1.f);

            if (out < 6) {
                cry_pi_11_lane(v, 1 << (5 - out), 1.f, ln);
            } else if (out == 6) {
                wave_cry_pi(v, 2, 1.f, wv, ln, xbuf);
            } else if (out == 7) {
                wave_cry_pi(v, 1, 1.f, wv, ln, xbuf);
            } else if (out == 8) {
                cry_pi_11_reg<8>(v, 1.f);
            } else {
                cry_pi_11_reg<4>(v, 1.f);
            }

            rot_block_apply(v, c4, s4, 1.f);
            cry_pi_10_11(v, -1.f);
            rot_block_apply(v, c4, s4, -1.f);
        }
    }

    // ---- probs: marginal |amp|^2 over qubits 6..11 (wave + reg bits) ----
    float acc = 0.f;
#pragma unroll
    for (int r = 0; r < 16; ++r) acc += v[r] * v[r];
    __syncthreads();                 // xbuf free for reuse
    xbuf[wv * 64 + ln] = acc;
    __syncthreads();
    if (wv == 0) {
        float t = xbuf[ln] + xbuf[64 + ln] + xbuf[128 + ln] + xbuf[192 + ln];
        out_probs[(size_t)b * 64 + ln] = t;
    }

    // ---- write final psi ----
    float* dst = out_psi + (size_t)b * 4096 + (ln << 6) + (wv << 4);
#pragma unroll
    for (int q = 0; q < 4; ++q)
        ((float4*)dst)[q] = make_float4(v[4*q], v[4*q+1], v[4*q+2], v[4*q+3]);
}

extern "C" void kernel_launch(void* const* d_in, const int* in_sizes, int n_in,
                              void* d_out, int out_size, void* d_ws, size_t ws_size,
                              hipStream_t stream) {
    const float* psi = (const float*)d_in[0];
    const int*   inp = (const int*)d_in[1];
    const float* ut  = (const float*)d_in[2];
    const float* nt  = (const float*)d_in[3];

    const int B = in_sizes[0] >> 12;          // 4096 amplitudes per state
    float* probs = (float*)d_out;             // (B, 64) first
    float* opsi  = probs + (size_t)B * 64;    // then (B, 4096)

    rvqe_kernel<<<B, 256, 0, stream>>>(psi, inp, ut, nt, probs, opsi);
}

// Round 3
// 91.124 us; speedup vs baseline: 1.1885x; 1.0371x over previous
//
#include <hip/hip_runtime.h>
#include <math.h>

// 8 waves (512 threads) per batch element. State psi (4096 fp32) split:
//   flat bits [11:6] = lane id (qubits 0..5, qubit i <-> lane bit 5-i)
//   flat bits [5:3]  = wave id (q6=bit2, q7=bit1, q8=bit0) <- LDS cross-wave
//   flat bits [2:0]  = reg  id (q9=bit2, q10=bit1, q11=bit0) <- in-register
//
// Neuron fusion: the quantum-neuron sequence
//   RB(+), crY(pi,10,11), RB(-), T, RB(+), crY(-pi,10,11), RB(-)
// where RB(sgn) is the fused rY(sgn*phi) on q10 (all 10 crY + bias commute),
// collapses to  M2 * T * M1  with M1 = RB(-)*C*RB(+), M2 = RB(-)*C'*RB(+):
// 4x4 matrices on the (q10,q11) subspace in u=cos^2(phi/2), d=sin^2(phi/2),
// p = cos*sin -- derived from ONE sincos(phi): u=.5+.5c, d=.5-.5c, p=.5s.
// T = crY(pi, ctrl q11, tgt out) touches only the two q11=1 components of
// the M1 output (w1, w3) -> shuffle/LDS-exchange just those.
// BitFlip folds into the load address.

#define NPLANE 512  // float2 slots per plane (8 waves * 64 lanes)

// M1: w = RB(-)*C*RB(+) * v   (basis m = 2*q10 + q11)
__device__ __forceinline__ void m1_apply(const float* v, float* w,
                                         float u, float d, float p) {
    w[0] =  u * v[0] - d * v[1] - p * v[2] - p * v[3];
    w[1] =  d * v[0] + u * v[1] + p * v[2] - p * v[3];
    w[2] = -p * v[0] - p * v[1] + d * v[2] - u * v[3];
    w[3] =  p * v[0] - p * v[1] + u * v[2] + d * v[3];
}

// M2: v = RB(-)*C'*RB(+) * w
__device__ __forceinline__ void m2_apply(float* v, const float* w,
                                         float u, float d, float p) {
    v[0] =  u * w[0] + d * w[1] - p * w[2] + p * w[3];
    v[1] = -d * w[0] + u * w[1] - p * w[2] - p * w[3];
    v[2] = -p * w[0] + p * w[1] + d * w[2] + u * w[3];
    v[3] = -p * w[0] - p * w[1] - u * w[2] + d * w[3];
}

__device__ __forceinline__ void lane_ry(float (&v)[8], int lm, float c, float s, int ln) {
    float ss = (ln & lm) ? s : -s;
#pragma unroll
    for (int r = 0; r < 8; ++r) {
        float p = __shfl_xor(v[r], lm, 64);
        v[r] = c * v[r] + ss * p;
    }
}

// cross-wave uncontrolled rY on wave-bit qubit (wm=4 -> q6, 2 -> q7, 1 -> q8)
// Double-buffered: exactly ONE barrier per exchange (writers of buffer X are
// separated from X's previous readers by the intervening exchange's barrier).
__device__ __forceinline__ void wave_ry(float (&v)[8], int wm, float c, float s,
                                        int wv, int ln, float2* buf) {
    const int slot = wv * 64 + ln;
#pragma unroll
    for (int q = 0; q < 4; ++q)
        buf[q * NPLANE + slot] = make_float2(v[2 * q], v[2 * q + 1]);
    __syncthreads();
    const int pslot = (wv ^ wm) * 64 + ln;
    float ss = (wv & wm) ? s : -s;
#pragma unroll
    for (int q = 0; q < 4; ++q) {
        float2 t = buf[q * NPLANE + pslot];
        v[2 * q]     = c * v[2 * q]     + ss * t.x;
        v[2 * q + 1] = c * v[2 * q + 1] + ss * t.y;
    }
}

__global__ __launch_bounds__(512) void rvqe_kernel(
    const float* __restrict__ psi_in,   // (B, 4096)
    const int*   __restrict__ inp,      // (6,)
    const float* __restrict__ ut,       // (2, 10)
    const float* __restrict__ nt,       // (2, 10, 11)
    float* __restrict__ out_probs,      // (B, 64)
    float* __restrict__ out_psi)        // (B, 4096)
{
    __shared__ float2 xbuf[2][4 * NPLANE];  // 2 x 16 KB

    const int b   = blockIdx.x;
    const int tid = threadIdx.x;
    const int ln  = tid & 63;
    const int wv  = tid >> 6;   // bit2=q6, bit1=q7, bit0=q8
    int bi = 0;                 // double-buffer index

    // BitFlip: fold X on input lanes into load address
    int flip = 0;
#pragma unroll
    for (int l = 0; l < 6; ++l)
        if (inp[l] == 1) flip |= 1 << (5 - l);

    float v[8];
    {
        const float* src = psi_in + (size_t)b * 4096 + (((ln ^ flip) & 63) << 6) + (wv << 3);
        float4 t0 = ((const float4*)src)[0];
        float4 t1 = ((const float4*)src)[1];
        v[0] = t0.x; v[1] = t0.y; v[2] = t0.z; v[3] = t0.w;
        v[4] = t1.x; v[5] = t1.y; v[6] = t1.z; v[7] = t1.w;
    }

    for (int s = 0; s < 2; ++s) {
        const float* uts = ut + s * 10;

        // ---- UnitaryLayer: rY(uts[i]) on qubit i ----
#pragma unroll
        for (int i = 0; i < 6; ++i) {
            float cc, ss;
            __sincosf(0.5f * uts[i], &ss, &cc);
            lane_ry(v, 1 << (5 - i), cc, ss, ln);
        }
        {
            float cc, ss;
            __sincosf(0.5f * uts[6], &ss, &cc);
            wave_ry(v, 4, cc, ss, wv, ln, xbuf[bi]); bi ^= 1;
            __sincosf(0.5f * uts[7], &ss, &cc);
            wave_ry(v, 2, cc, ss, wv, ln, xbuf[bi]); bi ^= 1;
            __sincosf(0.5f * uts[8], &ss, &cc);
            wave_ry(v, 1, cc, ss, wv, ln, xbuf[bi]); bi ^= 1;
            // q9 = reg bit 2: pairs (r, r+4)
            __sincosf(0.5f * uts[9], &ss, &cc);
#pragma unroll
            for (int r = 0; r < 4; ++r) {
                float a0 = v[r], a1 = v[r + 4];
                v[r]     = cc * a0 - ss * a1;
                v[r + 4] = ss * a0 + cc * a1;
            }
        }

        // ---- QuantumNeuronLayer per out lane ----
        for (int out = 0; out < 10; ++out) {
            const float* th = nt + (size_t)(s * 10 + out) * 11;

            // fused angle: bias + lane bits (q0..5) + wave bits (q6..8)
            float phi = th[10];
#pragma unroll
            for (int i = 0; i < 6; ++i)
                if ((ln >> (5 - i)) & 1) phi += th[i];
            if (wv & 4) phi += th[6];
            if (wv & 2) phi += th[7];
            if (wv & 1) phi += th[8];

            float sA, cA, sB, cB;
            __sincosf(phi, &sA, &cA);
            __sincosf(phi + th[9], &sB, &cB);
            float uA = 0.5f + 0.5f * cA, dA = 0.5f - 0.5f * cA, pA = 0.5f * sA;
            float uB = 0.5f + 0.5f * cB, dB = 0.5f - 0.5f * cB, pB = 0.5f * sB;

            float wA[4], wB[4];
            m1_apply(v,     wA, uA, dA, pA);   // group q9=0 (regs 0..3)
            m1_apply(v + 4, wB, uB, dB, pB);   // group q9=1 (regs 4..7)

            // T = crY(pi, ctrl q11, tgt out) on w1, w3 of each group
            if (out < 6) {
                const int lm = 1 << (5 - out);
                float ss = (ln & lm) ? 1.f : -1.f;
                wA[1] = ss * __shfl_xor(wA[1], lm, 64);
                wA[3] = ss * __shfl_xor(wA[3], lm, 64);
                wB[1] = ss * __shfl_xor(wB[1], lm, 64);
                wB[3] = ss * __shfl_xor(wB[3], lm, 64);
            } else if (out < 9) {
                const int wm = 1 << (8 - out);  // out6->4, out7->2, out8->1
                float2* buf = xbuf[bi]; bi ^= 1;
                const int slot = wv * 64 + ln;
                buf[slot]          = make_float2(wA[1], wA[3]);
                buf[NPLANE + slot] = make_float2(wB[1], wB[3]);
                __syncthreads();
                const int pslot = (wv ^ wm) * 64 + ln;
                float ss = (wv & wm) ? 1.f : -1.f;
                float2 tA = buf[pslot];
                float2 tB = buf[NPLANE + pslot];
                wA[1] = ss * tA.x; wA[3] = ss * tA.y;
                wB[1] = ss * tB.x; wB[3] = ss * tB.y;
            } else {  // out == 9: reg bit 2; new(q9=0) = -old(q9=1), new(q9=1) = +old(q9=0)
                float t1 = wA[1], t3 = wA[3];
                wA[1] = -wB[1]; wA[3] = -wB[3];
                wB[1] = t1;     wB[3] = t3;
            }

            m2_apply(v,     wA, uA, dA, pA);
            m2_apply(v + 4, wB, uB, dB, pB);
        }
    }

    // ---- probs: marginal |amp|^2 over qubits 6..11 (wave + reg bits) ----
    float acc = 0.f;
#pragma unroll
    for (int r = 0; r < 8; ++r) acc += v[r] * v[r];
    {
        float* pb = (float*)xbuf[bi];   // double-buffer invariant keeps this safe
        pb[wv * 64 + ln] = acc;
        __syncthreads();
        if (wv == 0) {
            float t = 0.f;
#pragma unroll
            for (int w = 0; w < 8; ++w) t += pb[w * 64 + ln];
            out_probs[(size_t)b * 64 + ln] = t;
        }
    }

    // ---- write final psi ----
    float* dst = out_psi + (size_t)b * 4096 + (ln << 6) + (wv << 3);
    ((float4*)dst)[0] = make_float4(v[0], v[1], v[2], v[3]);
    ((float4*)dst)[1] = make_float4(v[4], v[5], v[6], v[7]);
}

extern "C" void kernel_launch(void* const* d_in, const int* in_sizes, int n_in,
                              void* d_out, int out_size, void* d_ws, size_t ws_size,
                              hipStream_t stream) {
    const float* psi = (const float*)d_in[0];
    const int*   inp = (const int*)d_in[1];
    const float* ut  = (const float*)d_in[2];
    const float* nt  = (const float*)d_in[3];

    const int B = in_sizes[0] >> 12;          // 4096 amplitudes per state
    float* probs = (float*)d_out;             // (B, 64) first
    float* opsi  = probs + (size_t)B * 64;    // then (B, 4096)

    rvqe_kernel<<<B, 512, 0, stream>>>(psi, inp, ut, nt, probs, opsi);
}

// Round 4
// 85.819 us; speedup vs baseline: 1.2620x; 1.0618x over previous
//
#include <hip/hip_runtime.h>
#include <math.h>

// 8 waves (512 threads) per batch element. State psi (4096 fp32) split:
//   flat bits [11:6] = lane id (qubits 0..5, qubit i <-> lane bit 5-i)
//   flat bits [5:3]  = wave id (q6=4, q7=2, q8=1)   <- LDS cross-wave (b128)
//   flat bits [2:0]  = reg  id (q9=bit2, q10=bit1, q11=bit0) <- in-register
//
// Neuron: RB(+),crY(pi,10,11),RB(-),T,RB(+),crY(-pi,10,11),RB(-) collapses to
// M2 * T * M1 on the (q10,q11) 4-space, u=cos^2, d=sin^2, p=cos*sin from ONE
// sincos(phi) per q9-group. T = crY(pi, ctrl q11, tgt out) touches only the
// q11=1 components (the .y halves).
//
// DS-pressure optimizations (R4): DPP quad_perm for xor1/xor2 shuffles,
// compile-time masks everywhere (ds_swizzle not bpermute), b128 LDS
// exchanges, v_pk_fma_f32 packed math via ext_vector v2f.

typedef float v2f __attribute__((ext_vector_type(2)));

#define NSLOT 512  // 8 waves * 64 lanes

__device__ __forceinline__ v2f mk(float a, float b) { v2f r; r.x = a; r.y = b; return r; }

template <int XM>
__device__ __forceinline__ float shx(float x) {
    if constexpr (XM == 1) {        // quad_perm [1,0,3,2] = xor 1 (VALU, no DS)
        return __int_as_float(__builtin_amdgcn_update_dpp(
            0, __float_as_int(x), 0xB1, 0xF, 0xF, true));
    } else if constexpr (XM == 2) { // quad_perm [2,3,0,1] = xor 2
        return __int_as_float(__builtin_amdgcn_update_dpp(
            0, __float_as_int(x), 0x4E, 0xF, 0xF, true));
    } else {
        return __shfl_xor(x, XM, 64);
    }
}

template <int LM>
__device__ __forceinline__ void lane_ry_t(v2f (&V)[4], float c, float s, int ln) {
    float ss = (ln & LM) ? s : -s;
#pragma unroll
    for (int k = 0; k < 4; ++k) {
        v2f p = mk(shx<LM>(V[k].x), shx<LM>(V[k].y));
        V[k] = c * V[k] + ss * p;
    }
}

// cross-wave uncontrolled rY on wave-bit qubit via b128 LDS exchange.
// Double-buffered by caller: ONE barrier per exchange.
__device__ __forceinline__ void wave_ry(v2f (&V)[4], int wm, float c, float s,
                                        int wv, int ln, float4* buf) {
    const int slot = wv * 64 + ln;
    buf[slot]         = make_float4(V[0].x, V[0].y, V[1].x, V[1].y);
    buf[NSLOT + slot] = make_float4(V[2].x, V[2].y, V[3].x, V[3].y);
    __syncthreads();
    const int pslot = (wv ^ wm) * 64 + ln;
    float ss = (wv & wm) ? s : -s;
    float4 t0 = buf[pslot];
    float4 t1 = buf[NSLOT + pslot];
    V[0] = c * V[0] + ss * mk(t0.x, t0.y);
    V[1] = c * V[1] + ss * mk(t0.z, t0.w);
    V[2] = c * V[2] + ss * mk(t1.x, t1.y);
    V[3] = c * V[3] + ss * mk(t1.z, t1.w);
}

// One quantum neuron, OUT = target lane. V[0]={m0,m1} q9=0, V[1]={m2,m3} q9=0,
// V[2],V[3] = q9=1 group. buf only used for OUT in {6,7,8}.
template <int OUT>
__device__ __forceinline__ void neuron(v2f (&V)[4], const float* __restrict__ th,
                                       int wv, int ln, float4* buf) {
    // fused angle: bias + lane bits (tree) + wave bits (uniform)
    float a0 = (ln & 32) ? th[0] : 0.f;
    float a1 = (ln & 16) ? th[1] : 0.f;
    float a2 = (ln &  8) ? th[2] : 0.f;
    float a3 = (ln &  4) ? th[3] : 0.f;
    float a4 = (ln &  2) ? th[4] : 0.f;
    float a5 = (ln &  1) ? th[5] : 0.f;
    float wsum = th[10];
    if (wv & 4) wsum += th[6];
    if (wv & 2) wsum += th[7];
    if (wv & 1) wsum += th[8];
    float phi = ((a0 + a1) + (a2 + a3)) + ((a4 + a5) + wsum);

    float sA, cA, sB, cB;
    __sincosf(phi, &sA, &cA);
    __sincosf(phi + th[9], &sB, &cB);
    float uA = 0.5f + 0.5f * cA, dA = 0.5f - 0.5f * cA, pA = 0.5f * sA;
    float uB = 0.5f + 0.5f * cB, dB = 0.5f - 0.5f * cB, pB = 0.5f * sB;

    // M1: w = RB(-)*C*RB(+) * v
    v2f WA01 = mk(uA, dA) * V[0].x + mk(-dA, uA) * V[0].y + mk(-pA, pA) * V[1].x + mk(-pA, -pA) * V[1].y;
    v2f WA23 = mk(-pA, pA) * V[0].x + mk(-pA, -pA) * V[0].y + mk(dA, uA) * V[1].x + mk(-uA, dA) * V[1].y;
    v2f WB01 = mk(uB, dB) * V[2].x + mk(-dB, uB) * V[2].y + mk(-pB, pB) * V[3].x + mk(-pB, -pB) * V[3].y;
    v2f WB23 = mk(-pB, pB) * V[2].x + mk(-pB, -pB) * V[2].y + mk(dB, uB) * V[3].x + mk(-uB, dB) * V[3].y;

    // T = crY(pi, ctrl q11, tgt OUT) on the q11=1 (.y) components
    if constexpr (OUT < 6) {
        constexpr int LM = 1 << (5 - OUT);
        float ss = (ln & LM) ? 1.f : -1.f;
        WA01.y = ss * shx<LM>(WA01.y);
        WA23.y = ss * shx<LM>(WA23.y);
        WB01.y = ss * shx<LM>(WB01.y);
        WB23.y = ss * shx<LM>(WB23.y);
    } else if constexpr (OUT < 9) {
        constexpr int WM = 1 << (8 - OUT);
        const int slot = wv * 64 + ln;
        buf[slot] = make_float4(WA01.y, WA23.y, WB01.y, WB23.y);
        __syncthreads();
        const int pslot = (wv ^ WM) * 64 + ln;
        float ss = (wv & WM) ? 1.f : -1.f;
        float4 t = buf[pslot];
        WA01.y = ss * t.x; WA23.y = ss * t.y; WB01.y = ss * t.z; WB23.y = ss * t.w;
    } else {  // OUT == 9: q9 = reg-group bit; new(A) = -old(B), new(B) = old(A)
        float t1 = WA01.y, t3 = WA23.y;
        WA01.y = -WB01.y; WA23.y = -WB23.y;
        WB01.y = t1;      WB23.y = t3;
    }

    // M2: v = RB(-)*C'*RB(+) * w
    V[0] = mk(uA, -dA) * WA01.x + mk(dA, uA) * WA01.y + mk(-pA, -pA) * WA23.x + mk(pA, -pA) * WA23.y;
    V[1] = mk(-pA, -pA) * WA01.x + mk(pA, -pA) * WA01.y + mk(dA, -uA) * WA23.x + mk(uA, dA) * WA23.y;
    V[2] = mk(uB, -dB) * WB01.x + mk(dB, uB) * WB01.y + mk(-pB, -pB) * WB23.x + mk(pB, -pB) * WB23.y;
    V[3] = mk(-pB, -pB) * WB01.x + mk(pB, -pB) * WB01.y + mk(dB, -uB) * WB23.x + mk(uB, dB) * WB23.y;
}

__global__ __launch_bounds__(512, 4) void rvqe_kernel(
    const float* __restrict__ psi_in,   // (B, 4096)
    const int*   __restrict__ inp,      // (6,)
    const float* __restrict__ ut,       // (2, 10)
    const float* __restrict__ nt,       // (2, 10, 11)
    float* __restrict__ out_probs,      // (B, 64)
    float* __restrict__ out_psi)        // (B, 4096)
{
    __shared__ float4 xbuf[2][2 * NSLOT];  // 2 x 16 KB

    const int b   = blockIdx.x;
    const int tid = threadIdx.x;
    const int ln  = tid & 63;
    const int wv  = tid >> 6;   // bit2=q6, bit1=q7, bit0=q8
    int bi = 0;

    // BitFlip: fold X on input lanes into load address
    int flip = 0;
#pragma unroll
    for (int l = 0; l < 6; ++l)
        if (inp[l] == 1) flip |= 1 << (5 - l);

    v2f V[4];
    {
        const float* src = psi_in + (size_t)b * 4096 + (((ln ^ flip) & 63) << 6) + (wv << 3);
        float4 t0 = ((const float4*)src)[0];
        float4 t1 = ((const float4*)src)[1];
        V[0] = mk(t0.x, t0.y); V[1] = mk(t0.z, t0.w);
        V[2] = mk(t1.x, t1.y); V[3] = mk(t1.z, t1.w);
    }

    for (int s = 0; s < 2; ++s) {
        const float* uts = ut + s * 10;
        const float* nts = nt + (size_t)s * 110;

        // ---- UnitaryLayer: rY(uts[i]) on qubit i ----
        {
            float cc, ss;
            __sincosf(0.5f * uts[0], &ss, &cc); lane_ry_t<32>(V, cc, ss, ln);
            __sincosf(0.5f * uts[1], &ss, &cc); lane_ry_t<16>(V, cc, ss, ln);
            __sincosf(0.5f * uts[2], &ss, &cc); lane_ry_t<8>(V, cc, ss, ln);
            __sincosf(0.5f * uts[3], &ss, &cc); lane_ry_t<4>(V, cc, ss, ln);
            __sincosf(0.5f * uts[4], &ss, &cc); lane_ry_t<2>(V, cc, ss, ln);
            __sincosf(0.5f * uts[5], &ss, &cc); lane_ry_t<1>(V, cc, ss, ln);
            __sincosf(0.5f * uts[6], &ss, &cc);
            wave_ry(V, 4, cc, ss, wv, ln, xbuf[bi]); bi ^= 1;
            __sincosf(0.5f * uts[7], &ss, &cc);
            wave_ry(V, 2, cc, ss, wv, ln, xbuf[bi]); bi ^= 1;
            __sincosf(0.5f * uts[8], &ss, &cc);
            wave_ry(V, 1, cc, ss, wv, ln, xbuf[bi]); bi ^= 1;
            __sincosf(0.5f * uts[9], &ss, &cc);
            // q9 = reg-group bit: A<->B
            v2f n0 = cc * V[0] - ss * V[2];
            v2f n2 = ss * V[0] + cc * V[2];
            v2f n1 = cc * V[1] - ss * V[3];
            v2f n3 = ss * V[1] + cc * V[3];
            V[0] = n0; V[1] = n1; V[2] = n2; V[3] = n3;
        }

        // ---- QuantumNeuronLayer, fully unrolled (compile-time masks) ----
        neuron<0>(V, nts + 0 * 11, wv, ln, nullptr);
        neuron<1>(V, nts + 1 * 11, wv, ln, nullptr);
        neuron<2>(V, nts + 2 * 11, wv, ln, nullptr);
        neuron<3>(V, nts + 3 * 11, wv, ln, nullptr);
        neuron<4>(V, nts + 4 * 11, wv, ln, nullptr);
        neuron<5>(V, nts + 5 * 11, wv, ln, nullptr);
        neuron<6>(V, nts + 6 * 11, wv, ln, xbuf[bi]); bi ^= 1;
        neuron<7>(V, nts + 7 * 11, wv, ln, xbuf[bi]); bi ^= 1;
        neuron<8>(V, nts + 8 * 11, wv, ln, xbuf[bi]); bi ^= 1;
        neuron<9>(V, nts + 9 * 11, wv, ln, nullptr);
    }

    // ---- probs: marginal |amp|^2 over qubits 6..11 (wave + reg bits) ----
    float acc = 0.f;
#pragma unroll
    for (int k = 0; k < 4; ++k) acc += V[k].x * V[k].x + V[k].y * V[k].y;
    {
        float* pb = (float*)&xbuf[bi][0];  // dbuf invariant: safe to write pre-barrier
        pb[wv * 64 + ln] = acc;
        __syncthreads();
        if (wv == 0) {
            float t = 0.f;
#pragma unroll
            for (int w = 0; w < 8; ++w) t += pb[w * 64 + ln];
            out_probs[(size_t)b * 64 + ln] = t;
        }
    }

    // ---- write final psi ----
    float* dst = out_psi + (size_t)b * 4096 + (ln << 6) + (wv << 3);
    ((float4*)dst)[0] = make_float4(V[0].x, V[0].y, V[1].x, V[1].y);
    ((float4*)dst)[1] = make_float4(V[2].x, V[2].y, V[3].x, V[3].y);
}

extern "C" void kernel_launch(void* const* d_in, const int* in_sizes, int n_in,
                              void* d_out, int out_size, void* d_ws, size_t ws_size,
                              hipStream_t stream) {
    const float* psi = (const float*)d_in[0];
    const int*   inp = (const int*)d_in[1];
    const float* ut  = (const float*)d_in[2];
    const float* nt  = (const float*)d_in[3];

    const int B = in_sizes[0] >> 12;          // 4096 amplitudes per state
    float* probs = (float*)d_out;             // (B, 64) first
    float* opsi  = probs + (size_t)B * 64;    // then (B, 4096)

    rvqe_kernel<<<B, 512, 0, stream>>>(psi, inp, ut, nt, probs, opsi);
}

// Round 5
// 84.196 us; speedup vs baseline: 1.2863x; 1.0193x over previous
//
#include <hip/hip_runtime.h>
#include <math.h>

// 8 waves (512 threads) per batch element. State psi (4096 fp32) split:
//   flat bits [11:6] = lane id (qubits 0..5, qubit i <-> lane bit 5-i)
//   flat bits [5:3]  = wave id (q6=4, q7=2, q8=1)   <- LDS cross-wave (b128)
//   flat bits [2:0]  = reg  id (q9=bit2, q10=bit1, q11=bit0) <- in-register
//
// Neuron = RB(+),crY(pi,10,11),RB(-),T,RB(+),crY(-pi,10,11),RB(-), where RB is
// the fused rY(phi) on q10 (all 10 crY + bias commute -> one angle per basis
// state). R5: apply it EXACTLY in that factorized form -- each RB is 4 pk-ops
// on the (q10,q11) 4-space, the crY(+-pi) in the middle is a component swap
// whose signs fold into the following RB (verified == the dense M1/M2 4x4s).
// T = crY(pi, ctrl q11, tgt out) touches only the q11=1 (.y) components.
//
// Cross-lane: xor1/xor2 via DPP quad_perm, xor8 via DPP row_ror:8 (all VALU);
// xor4/16/32 via ds_swizzle; wave bits via b128 LDS exchange, double-buffered
// (one barrier per exchange). BitFlip folds into the load address.

typedef float v2f __attribute__((ext_vector_type(2)));

#define NSLOT 512  // 8 waves * 64 lanes

__device__ __forceinline__ v2f mk(float a, float b) { v2f r; r.x = a; r.y = b; return r; }

template <int XM>
__device__ __forceinline__ float shx(float x) {
    if constexpr (XM == 1) {        // quad_perm [1,0,3,2] = xor 1 (VALU)
        return __int_as_float(__builtin_amdgcn_update_dpp(
            0, __float_as_int(x), 0xB1, 0xF, 0xF, true));
    } else if constexpr (XM == 2) { // quad_perm [2,3,0,1] = xor 2 (VALU)
        return __int_as_float(__builtin_amdgcn_update_dpp(
            0, __float_as_int(x), 0x4E, 0xF, 0xF, true));
    } else if constexpr (XM == 8) { // row_ror:8 -> (i+8)%16 == i^8 (VALU)
        return __int_as_float(__builtin_amdgcn_update_dpp(
            0, __float_as_int(x), 0x128, 0xF, 0xF, true));
    } else {
        return __shfl_xor(x, XM, 64);
    }
}

template <int LM>
__device__ __forceinline__ void lane_ry_t(v2f (&V)[4], float c, float s, int ln) {
    float ss = (ln & LM) ? s : -s;
#pragma unroll
    for (int k = 0; k < 4; ++k) {
        v2f p = mk(shx<LM>(V[k].x), shx<LM>(V[k].y));
        V[k] = c * V[k] + ss * p;
    }
}

// cross-wave uncontrolled rY on wave-bit qubit via b128 LDS exchange.
__device__ __forceinline__ void wave_ry(v2f (&V)[4], int wm, float c, float s,
                                        int wv, int ln, float4* buf) {
    const int slot = wv * 64 + ln;
    buf[slot]         = make_float4(V[0].x, V[0].y, V[1].x, V[1].y);
    buf[NSLOT + slot] = make_float4(V[2].x, V[2].y, V[3].x, V[3].y);
    __syncthreads();
    const int pslot = (wv ^ wm) * 64 + ln;
    float ss = (wv & wm) ? s : -s;
    float4 t0 = buf[pslot];
    float4 t1 = buf[NSLOT + pslot];
    V[0] = c * V[0] + ss * mk(t0.x, t0.y);
    V[1] = c * V[1] + ss * mk(t0.z, t0.w);
    V[2] = c * V[2] + ss * mk(t1.x, t1.y);
    V[3] = c * V[3] + ss * mk(t1.z, t1.w);
}

// First half of the neuron on one q9-group: RB(+), crY(pi,10,11), RB(-).
// In basis m=2*q10+q11 with V0=(m0,m1), V1=(m2,m3):
//   t0=(a0,a1)=c*V0-s*V1; t1=(a2,a3)=s*V0+c*V1; C: (a2,a3)->(-a3,a2)
//   u0=(w0,w1)=c*t0+(-s,s)*swap(t1); u1=(w2,w3)=-s*t0+(-c,c)*swap(t1)
__device__ __forceinline__ void half1(v2f V0, v2f V1, float c, float s,
                                      v2f& u0, v2f& u1) {
    v2f t0 = c * V0 - s * V1;
    v2f t1 = s * V0 + c * V1;
    v2f t1s = __builtin_shufflevector(t1, t1, 1, 0);
    u0 =  c * t0 + mk(-s,  s) * t1s;
    u1 = -s * t0 + mk(-c,  c) * t1s;
}

// Second half: RB(+), crY(-pi,10,11), RB(-).  C': (b2,b3)->(b3,-b2)
__device__ __forceinline__ void half2(v2f& V0, v2f& V1, float c, float s,
                                      v2f u0, v2f u1) {
    v2f r0 = c * u0 - s * u1;
    v2f r1 = s * u0 + c * u1;
    v2f r1s = __builtin_shufflevector(r1, r1, 1, 0);
    V0 =  c * r0 + mk( s, -s) * r1s;
    V1 = -s * r0 + mk( c, -c) * r1s;
}

// One quantum neuron, OUT = target qubit. V[0],V[1] = q9=0 group; V[2],V[3] =
// q9=1 group. buf only used for OUT in {6,7,8}.
template <int OUT>
__device__ __forceinline__ void neuron(v2f (&V)[4], const float* __restrict__ th,
                                       int wv, int ln, float4* buf) {
    // fused angle (HALF angle for the RB rotations)
    float a0 = (ln & 32) ? th[0] : 0.f;
    float a1 = (ln & 16) ? th[1] : 0.f;
    float a2 = (ln &  8) ? th[2] : 0.f;
    float a3 = (ln &  4) ? th[3] : 0.f;
    float a4 = (ln &  2) ? th[4] : 0.f;
    float a5 = (ln &  1) ? th[5] : 0.f;
    float wsum = th[10];
    if (wv & 4) wsum += th[6];
    if (wv & 2) wsum += th[7];
    if (wv & 1) wsum += th[8];
    float phih = 0.5f * (((a0 + a1) + (a2 + a3)) + ((a4 + a5) + wsum));

    float sA, cA, sB, cB;
    __sincosf(phih, &sA, &cA);
    __sincosf(phih + 0.5f * th[9], &sB, &cB);

    v2f uA0, uA1, uB0, uB1;
    half1(V[0], V[1], cA, sA, uA0, uA1);
    half1(V[2], V[3], cB, sB, uB0, uB1);

    // T = crY(pi, ctrl q11, tgt OUT) on the q11=1 (.y) components
    if constexpr (OUT < 6) {
        constexpr int LM = 1 << (5 - OUT);
        float ss = (ln & LM) ? 1.f : -1.f;
        uA0.y = ss * shx<LM>(uA0.y);
        uA1.y = ss * shx<LM>(uA1.y);
        uB0.y = ss * shx<LM>(uB0.y);
        uB1.y = ss * shx<LM>(uB1.y);
    } else if constexpr (OUT < 9) {
        constexpr int WM = 1 << (8 - OUT);
        const int slot = wv * 64 + ln;
        buf[slot] = make_float4(uA0.y, uA1.y, uB0.y, uB1.y);
        __syncthreads();
        const int pslot = (wv ^ WM) * 64 + ln;
        float ss = (wv & WM) ? 1.f : -1.f;
        float4 t = buf[pslot];
        uA0.y = ss * t.x; uA1.y = ss * t.y; uB0.y = ss * t.z; uB1.y = ss * t.w;
    } else {  // OUT == 9: q9 = reg-group bit; new(A) = -old(B), new(B) = old(A)
        float t1 = uA0.y, t3 = uA1.y;
        uA0.y = -uB0.y; uA1.y = -uB1.y;
        uB0.y = t1;     uB1.y = t3;
    }

    half2(V[0], V[1], cA, sA, uA0, uA1);
    half2(V[2], V[3], cB, sB, uB0, uB1);
}

__global__ __launch_bounds__(512, 4) void rvqe_kernel(
    const float* __restrict__ psi_in,   // (B, 4096)
    const int*   __restrict__ inp,      // (6,)
    const float* __restrict__ ut,       // (2, 10)
    const float* __restrict__ nt,       // (2, 10, 11)
    float* __restrict__ out_probs,      // (B, 64)
    float* __restrict__ out_psi)        // (B, 4096)
{
    __shared__ float4 xbuf[2][2 * NSLOT];  // 2 x 16 KB

    const int b   = blockIdx.x;
    const int tid = threadIdx.x;
    const int ln  = tid & 63;
    const int wv  = tid >> 6;   // bit2=q6, bit1=q7, bit0=q8
    int bi = 0;

    // BitFlip: fold X on input lanes into load address
    int flip = 0;
#pragma unroll
    for (int l = 0; l < 6; ++l)
        if (inp[l] == 1) flip |= 1 << (5 - l);

    v2f V[4];
    {
        const float* src = psi_in + (size_t)b * 4096 + (((ln ^ flip) & 63) << 6) + (wv << 3);
        float4 t0 = ((const float4*)src)[0];
        float4 t1 = ((const float4*)src)[1];
        V[0] = mk(t0.x, t0.y); V[1] = mk(t0.z, t0.w);
        V[2] = mk(t1.x, t1.y); V[3] = mk(t1.z, t1.w);
    }

    for (int s = 0; s < 2; ++s) {
        const float* uts = ut + s * 10;
        const float* nts = nt + (size_t)s * 110;

        // ---- UnitaryLayer: rY(uts[i]) on qubit i ----
        {
            float cc, ss;
            __sincosf(0.5f * uts[0], &ss, &cc); lane_ry_t<32>(V, cc, ss, ln);
            __sincosf(0.5f * uts[1], &ss, &cc); lane_ry_t<16>(V, cc, ss, ln);
            __sincosf(0.5f * uts[2], &ss, &cc); lane_ry_t<8>(V, cc, ss, ln);
            __sincosf(0.5f * uts[3], &ss, &cc); lane_ry_t<4>(V, cc, ss, ln);
            __sincosf(0.5f * uts[4], &ss, &cc); lane_ry_t<2>(V, cc, ss, ln);
            __sincosf(0.5f * uts[5], &ss, &cc); lane_ry_t<1>(V, cc, ss, ln);
            __sincosf(0.5f * uts[6], &ss, &cc);
            wave_ry(V, 4, cc, ss, wv, ln, xbuf[bi]); bi ^= 1;
            __sincosf(0.5f * uts[7], &ss, &cc);
            wave_ry(V, 2, cc, ss, wv, ln, xbuf[bi]); bi ^= 1;
            __sincosf(0.5f * uts[8], &ss, &cc);
            wave_ry(V, 1, cc, ss, wv, ln, xbuf[bi]); bi ^= 1;
            __sincosf(0.5f * uts[9], &ss, &cc);
            // q9 = reg-group bit: A<->B
            v2f n0 = cc * V[0] - ss * V[2];
            v2f n2 = ss * V[0] + cc * V[2];
            v2f n1 = cc * V[1] - ss * V[3];
            v2f n3 = ss * V[1] + cc * V[3];
            V[0] = n0; V[1] = n1; V[2] = n2; V[3] = n3;
        }

        // ---- QuantumNeuronLayer, fully unrolled (compile-time masks) ----
        neuron<0>(V, nts + 0 * 11, wv, ln, nullptr);
        neuron<1>(V, nts + 1 * 11, wv, ln, nullptr);
        neuron<2>(V, nts + 2 * 11, wv, ln, nullptr);
        neuron<3>(V, nts + 3 * 11, wv, ln, nullptr);
        neuron<4>(V, nts + 4 * 11, wv, ln, nullptr);
        neuron<5>(V, nts + 5 * 11, wv, ln, nullptr);
        neuron<6>(V, nts + 6 * 11, wv, ln, xbuf[bi]); bi ^= 1;
        neuron<7>(V, nts + 7 * 11, wv, ln, xbuf[bi]); bi ^= 1;
        neuron<8>(V, nts + 8 * 11, wv, ln, xbuf[bi]); bi ^= 1;
        neuron<9>(V, nts + 9 * 11, wv, ln, nullptr);
    }

    // ---- probs: marginal |amp|^2 over qubits 6..11 (wave + reg bits) ----
    float acc = 0.f;
#pragma unroll
    for (int k = 0; k < 4; ++k) acc += V[k].x * V[k].x + V[k].y * V[k].y;
    {
        float* pb = (float*)&xbuf[bi][0];  // dbuf invariant: safe to write pre-barrier
        pb[wv * 64 + ln] = acc;
        __syncthreads();
        if (wv == 0) {
            float t = 0.f;
#pragma unroll
            for (int w = 0; w < 8; ++w) t += pb[w * 64 + ln];
            out_probs[(size_t)b * 64 + ln] = t;
        }
    }

    // ---- write final psi ----
    float* dst = out_psi + (size_t)b * 4096 + (ln << 6) + (wv << 3);
    ((float4*)dst)[0] = make_float4(V[0].x, V[0].y, V[1].x, V[1].y);
    ((float4*)dst)[1] = make_float4(V[2].x, V[2].y, V[3].x, V[3].y);
}

extern "C" void kernel_launch(void* const* d_in, const int* in_sizes, int n_in,
                              void* d_out, int out_size, void* d_ws, size_t ws_size,
                              hipStream_t stream) {
    const float* psi = (const float*)d_in[0];
    const int*   inp = (const int*)d_in[1];
    const float* ut  = (const float*)d_in[2];
    const float* nt  = (const float*)d_in[3];

    const int B = in_sizes[0] >> 12;          // 4096 amplitudes per state
    float* probs = (float*)d_out;             // (B, 64) first
    float* opsi  = probs + (size_t)B * 64;    // then (B, 4096)

    rvqe_kernel<<<B, 512, 0, stream>>>(psi, inp, ut, nt, probs, opsi);
}

// Round 6
// 83.932 us; speedup vs baseline: 1.2904x; 1.0031x over previous
//
#include <hip/hip_runtime.h>
#include <math.h>

// 8 waves (512 threads) per batch element. State psi (4096 fp32) split:
//   flat bits [11:6] = lane id (qubits 0..5, qubit i <-> lane bit 5-i)
//   flat bits [5:3]  = wave id (q6=4, q7=2, q8=1)   <- LDS cross-wave (b128)
//   flat bits [2:0]  = reg  id (q9=bit2, q10=bit1, q11=bit0) <- in-register
//
// Neuron = RB(+),crY(pi,10,11),RB(-),T,RB(+),crY(-pi,10,11),RB(-), applied in
// factorized form (R5). R6: ALL sincos via native v_sin_f32/v_cos_f32
// (input pre-scaled by 1/2pi) instead of __sincosf -- testing the hypothesis
// that library sincos expansion (~50+ instr each, ~50 calls/wave) is the
// hidden dominant VALU term across R1-R5.

typedef float v2f __attribute__((ext_vector_type(2)));

#define NSLOT 512  // 8 waves * 64 lanes

__device__ __forceinline__ v2f mk(float a, float b) { v2f r; r.x = a; r.y = b; return r; }

// native sincos: v_sin_f32/v_cos_f32 take revolutions (D = sin(S0*2pi)).
// |angle| here <= ~25 rad (~4 revolutions) -- well inside HW range.
__device__ __forceinline__ void fast_sincos(float a, float* s, float* c) {
    float r = a * 0.15915494309189535f;  // 1/(2*pi)
    *s = __builtin_amdgcn_sinf(r);
    *c = __builtin_amdgcn_cosf(r);
}

template <int XM>
__device__ __forceinline__ float shx(float x) {
    if constexpr (XM == 1) {        // quad_perm [1,0,3,2] = xor 1 (VALU)
        return __int_as_float(__builtin_amdgcn_update_dpp(
            0, __float_as_int(x), 0xB1, 0xF, 0xF, true));
    } else if constexpr (XM == 2) { // quad_perm [2,3,0,1] = xor 2 (VALU)
        return __int_as_float(__builtin_amdgcn_update_dpp(
            0, __float_as_int(x), 0x4E, 0xF, 0xF, true));
    } else if constexpr (XM == 8) { // row_ror:8 -> (i+8)%16 == i^8 (VALU)
        return __int_as_float(__builtin_amdgcn_update_dpp(
            0, __float_as_int(x), 0x128, 0xF, 0xF, true));
    } else {
        return __shfl_xor(x, XM, 64);
    }
}

template <int LM>
__device__ __forceinline__ void lane_ry_t(v2f (&V)[4], float c, float s, int ln) {
    float ss = (ln & LM) ? s : -s;
#pragma unroll
    for (int k = 0; k < 4; ++k) {
        v2f p = mk(shx<LM>(V[k].x), shx<LM>(V[k].y));
        V[k] = c * V[k] + ss * p;
    }
}

// cross-wave uncontrolled rY on wave-bit qubit via b128 LDS exchange.
__device__ __forceinline__ void wave_ry(v2f (&V)[4], int wm, float c, float s,
                                        int wv, int ln, float4* buf) {
    const int slot = wv * 64 + ln;
    buf[slot]         = make_float4(V[0].x, V[0].y, V[1].x, V[1].y);
    buf[NSLOT + slot] = make_float4(V[2].x, V[2].y, V[3].x, V[3].y);
    __syncthreads();
    const int pslot = (wv ^ wm) * 64 + ln;
    float ss = (wv & wm) ? s : -s;
    float4 t0 = buf[pslot];
    float4 t1 = buf[NSLOT + pslot];
    V[0] = c * V[0] + ss * mk(t0.x, t0.y);
    V[1] = c * V[1] + ss * mk(t0.z, t0.w);
    V[2] = c * V[2] + ss * mk(t1.x, t1.y);
    V[3] = c * V[3] + ss * mk(t1.z, t1.w);
}

// First half of the neuron on one q9-group: RB(+), crY(pi,10,11), RB(-).
__device__ __forceinline__ void half1(v2f V0, v2f V1, float c, float s,
                                      v2f& u0, v2f& u1) {
    v2f t0 = c * V0 - s * V1;
    v2f t1 = s * V0 + c * V1;
    v2f t1s = __builtin_shufflevector(t1, t1, 1, 0);
    u0 =  c * t0 + mk(-s,  s) * t1s;
    u1 = -s * t0 + mk(-c,  c) * t1s;
}

// Second half: RB(+), crY(-pi,10,11), RB(-).
__device__ __forceinline__ void half2(v2f& V0, v2f& V1, float c, float s,
                                      v2f u0, v2f u1) {
    v2f r0 = c * u0 - s * u1;
    v2f r1 = s * u0 + c * u1;
    v2f r1s = __builtin_shufflevector(r1, r1, 1, 0);
    V0 =  c * r0 + mk( s, -s) * r1s;
    V1 = -s * r0 + mk( c, -c) * r1s;
}

// One quantum neuron, OUT = target qubit. V[0],V[1] = q9=0 group; V[2],V[3] =
// q9=1 group. buf only used for OUT in {6,7,8}.
template <int OUT>
__device__ __forceinline__ void neuron(v2f (&V)[4], const float* __restrict__ th,
                                       int wv, int ln, float4* buf) {
    // fused angle (HALF angle for the RB rotations)
    float a0 = (ln & 32) ? th[0] : 0.f;
    float a1 = (ln & 16) ? th[1] : 0.f;
    float a2 = (ln &  8) ? th[2] : 0.f;
    float a3 = (ln &  4) ? th[3] : 0.f;
    float a4 = (ln &  2) ? th[4] : 0.f;
    float a5 = (ln &  1) ? th[5] : 0.f;
    float wsum = th[10];
    if (wv & 4) wsum += th[6];
    if (wv & 2) wsum += th[7];
    if (wv & 1) wsum += th[8];
    float phih = 0.5f * (((a0 + a1) + (a2 + a3)) + ((a4 + a5) + wsum));

    float sA, cA, sB, cB;
    fast_sincos(phih, &sA, &cA);
    fast_sincos(phih + 0.5f * th[9], &sB, &cB);

    v2f uA0, uA1, uB0, uB1;
    half1(V[0], V[1], cA, sA, uA0, uA1);
    half1(V[2], V[3], cB, sB, uB0, uB1);

    // T = crY(pi, ctrl q11, tgt OUT) on the q11=1 (.y) components
    if constexpr (OUT < 6) {
        constexpr int LM = 1 << (5 - OUT);
        float ss = (ln & LM) ? 1.f : -1.f;
        uA0.y = ss * shx<LM>(uA0.y);
        uA1.y = ss * shx<LM>(uA1.y);
        uB0.y = ss * shx<LM>(uB0.y);
        uB1.y = ss * shx<LM>(uB1.y);
    } else if constexpr (OUT < 9) {
        constexpr int WM = 1 << (8 - OUT);
        const int slot = wv * 64 + ln;
        buf[slot] = make_float4(uA0.y, uA1.y, uB0.y, uB1.y);
        __syncthreads();
        const int pslot = (wv ^ WM) * 64 + ln;
        float ss = (wv & WM) ? 1.f : -1.f;
        float4 t = buf[pslot];
        uA0.y = ss * t.x; uA1.y = ss * t.y; uB0.y = ss * t.z; uB1.y = ss * t.w;
    } else {  // OUT == 9: q9 = reg-group bit; new(A) = -old(B), new(B) = old(A)
        float t1 = uA0.y, t3 = uA1.y;
        uA0.y = -uB0.y; uA1.y = -uB1.y;
        uB0.y = t1;     uB1.y = t3;
    }

    half2(V[0], V[1], cA, sA, uA0, uA1);
    half2(V[2], V[3], cB, sB, uB0, uB1);
}

__global__ __launch_bounds__(512, 4) void rvqe_kernel(
    const float* __restrict__ psi_in,   // (B, 4096)
    const int*   __restrict__ inp,      // (6,)
    const float* __restrict__ ut,       // (2, 10)
    const float* __restrict__ nt,       // (2, 10, 11)
    float* __restrict__ out_probs,      // (B, 64)
    float* __restrict__ out_psi)        // (B, 4096)
{
    __shared__ float4 xbuf[2][2 * NSLOT];  // 2 x 16 KB

    const int b   = blockIdx.x;
    const int tid = threadIdx.x;
    const int ln  = tid & 63;
    const int wv  = tid >> 6;   // bit2=q6, bit1=q7, bit0=q8
    int bi = 0;

    // BitFlip: fold X on input lanes into load address
    int flip = 0;
#pragma unroll
    for (int l = 0; l < 6; ++l)
        if (inp[l] == 1) flip |= 1 << (5 - l);

    v2f V[4];
    {
        const float* src = psi_in + (size_t)b * 4096 + (((ln ^ flip) & 63) << 6) + (wv << 3);
        float4 t0 = ((const float4*)src)[0];
        float4 t1 = ((const float4*)src)[1];
        V[0] = mk(t0.x, t0.y); V[1] = mk(t0.z, t0.w);
        V[2] = mk(t1.x, t1.y); V[3] = mk(t1.z, t1.w);
    }

    for (int s = 0; s < 2; ++s) {
        const float* uts = ut + s * 10;
        const float* nts = nt + (size_t)s * 110;

        // ---- UnitaryLayer: rY(uts[i]) on qubit i ----
        {
            float cc, ss;
            fast_sincos(0.5f * uts[0], &ss, &cc); lane_ry_t<32>(V, cc, ss, ln);
            fast_sincos(0.5f * uts[1], &ss, &cc); lane_ry_t<16>(V, cc, ss, ln);
            fast_sincos(0.5f * uts[2], &ss, &cc); lane_ry_t<8>(V, cc, ss, ln);
            fast_sincos(0.5f * uts[3], &ss, &cc); lane_ry_t<4>(V, cc, ss, ln);
            fast_sincos(0.5f * uts[4], &ss, &cc); lane_ry_t<2>(V, cc, ss, ln);
            fast_sincos(0.5f * uts[5], &ss, &cc); lane_ry_t<1>(V, cc, ss, ln);
            fast_sincos(0.5f * uts[6], &ss, &cc);
            wave_ry(V, 4, cc, ss, wv, ln, xbuf[bi]); bi ^= 1;
            fast_sincos(0.5f * uts[7], &ss, &cc);
            wave_ry(V, 2, cc, ss, wv, ln, xbuf[bi]); bi ^= 1;
            fast_sincos(0.5f * uts[8], &ss, &cc);
            wave_ry(V, 1, cc, ss, wv, ln, xbuf[bi]); bi ^= 1;
            fast_sincos(0.5f * uts[9], &ss, &cc);
            // q9 = reg-group bit: A<->B
            v2f n0 = cc * V[0] - ss * V[2];
            v2f n2 = ss * V[0] + cc * V[2];
            v2f n1 = cc * V[1] - ss * V[3];
            v2f n3 = ss * V[1] + cc * V[3];
            V[0] = n0; V[1] = n1; V[2] = n2; V[3] = n3;
        }

        // ---- QuantumNeuronLayer, fully unrolled (compile-time masks) ----
        neuron<0>(V, nts + 0 * 11, wv, ln, nullptr);
        neuron<1>(V, nts + 1 * 11, wv, ln, nullptr);
        neuron<2>(V, nts + 2 * 11, wv, ln, nullptr);
        neuron<3>(V, nts + 3 * 11, wv, ln, nullptr);
        neuron<4>(V, nts + 4 * 11, wv, ln, nullptr);
        neuron<5>(V, nts + 5 * 11, wv, ln, nullptr);
        neuron<6>(V, nts + 6 * 11, wv, ln, xbuf[bi]); bi ^= 1;
        neuron<7>(V, nts + 7 * 11, wv, ln, xbuf[bi]); bi ^= 1;
        neuron<8>(V, nts + 8 * 11, wv, ln, xbuf[bi]); bi ^= 1;
        neuron<9>(V, nts + 9 * 11, wv, ln, nullptr);
    }

    // ---- probs: marginal |amp|^2 over qubits 6..11 (wave + reg bits) ----
    float acc = 0.f;
#pragma unroll
    for (int k = 0; k < 4; ++k) acc += V[k].x * V[k].x + V[k].y * V[k].y;
    {
        float* pb = (float*)&xbuf[bi][0];  // dbuf invariant: safe to write pre-barrier
        pb[wv * 64 + ln] = acc;
        __syncthreads();
        if (wv == 0) {
            float t = 0.f;
#pragma unroll
            for (int w = 0; w < 8; ++w) t += pb[w * 64 + ln];
            out_probs[(size_t)b * 64 + ln] = t;
        }
    }

    // ---- write final psi ----
    float* dst = out_psi + (size_t)b * 4096 + (ln << 6) + (wv << 3);
    ((float4*)dst)[0] = make_float4(V[0].x, V[0].y, V[1].x, V[1].y);
    ((float4*)dst)[1] = make_float4(V[2].x, V[2].y, V[3].x, V[3].y);
}

extern "C" void kernel_launch(void* const* d_in, const int* in_sizes, int n_in,
                              void* d_out, int out_size, void* d_ws, size_t ws_size,
                              hipStream_t stream) {
    const float* psi = (const float*)d_in[0];
    const int*   inp = (const int*)d_in[1];
    const float* ut  = (const float*)d_in[2];
    const float* nt  = (const float*)d_in[3];

    const int B = in_sizes[0] >> 12;          // 4096 amplitudes per state
    float* probs = (float*)d_out;             // (B, 64) first
    float* opsi  = probs + (size_t)B * 64;    // then (B, 4096)

    rvqe_kernel<<<B, 512, 0, stream>>>(psi, inp, ut, nt, probs, opsi);
}